// Round 5
// baseline (3864.322 us; speedup 1.0000x reference)
//
#include <hip/hip_runtime.h>

#define BB 512
#define TT 512
#define FF 64
#define HH 128
#define G4 512
#define NCLS 10
#define HBP 136          // padded h row (shorts)
#define ABP 516          // padded gate row (floats)
#define NCMAX 64

typedef __attribute__((ext_vector_type(8))) short short8;
typedef __attribute__((ext_vector_type(4))) float f32x4;

__device__ __forceinline__ float sigf(float x) { return 1.0f / (1.0f + __expf(-x)); }
__device__ __forceinline__ float tanhfast(float x) { return 2.0f / (1.0f + __expf(-2.0f * x)) - 1.0f; }
__device__ __forceinline__ unsigned short f2bf(float f) {
    union { float f; unsigned u; } v; v.f = f;
    unsigned r = v.u + 0x7FFFu + ((v.u >> 16) & 1u);
    return (unsigned short)(r >> 16);
}

// ---- flag protocol (round-4 proven idioms) --------------------------------
__device__ __forceinline__ void wait_flag(int* f) {
    if (threadIdx.x == 0) {
        while (__hip_atomic_load(f, __ATOMIC_ACQUIRE, __HIP_MEMORY_SCOPE_AGENT) == 0)
            __builtin_amdgcn_s_sleep(2);
    }
    __syncthreads();
    (void)__hip_atomic_load(f, __ATOMIC_ACQUIRE, __HIP_MEMORY_SCOPE_AGENT);
}
__device__ __forceinline__ void set_flag(int* f) {
    __threadfence();
    __syncthreads();
    if (threadIdx.x == 0)
        __hip_atomic_fetch_add(f, 1, __ATOMIC_RELEASE, __HIP_MEMORY_SCOPE_AGENT);
}

// ---------------------------------------------------------------------------
// Recurrent scan (h @ W_hh^T only; xp precomputed, bias folded into xp).
// One block = 16 batch rows (bg), 16 waves. Wave w owns gates [w*32,w*32+32),
// KT=4 stationary bf16 weight frags. Per step: acc init from prefetched xp,
// 8 MFMA, in-lane activations (wave-uniform gate type), abuf round-trip,
// state update (wave w = row w, lanes -> units l, l+64).
// ---------------------------------------------------------------------------
template<bool IS_L1>
__device__ void scan_layer(
    const float* __restrict__ xp,          // [buf][bg][tl][row][512] fp32 (bias included)
    const float* __restrict__ w_hh,
    unsigned short* __restrict__ out1,     // [buf][bg][tl][row][128] bf16 (L1 only)
    float* __restrict__ h2s,               // (L2 only)
    int* __restrict__ f_in,                // row [NCMAX] for this bg
    int* __restrict__ f_done,
    int* __restrict__ f_guard,             // L1: f_xp2 row (out1 buffer reuse guard)
    int bg, int Tc, int NC,
    unsigned short* hb, float* abuf)
{
    const int tid = threadIdx.x;
    const int w = tid >> 6, l = tid & 63, lm = l & 15, kb = l >> 4;
    const int gbase = w * 32;
    const int type = w >> 2;               // 0:i 1:f 2:g 3:o (wave-uniform)

    short8 bf0[4], bf1[4];
    {
        const int g0 = gbase + lm, g1 = gbase + 16 + lm;
        #pragma unroll
        for (int kt = 0; kt < 4; kt++) {
            const float* s0 = w_hh + (size_t)g0 * HH + kt * 32 + kb * 8;
            const float* s1 = w_hh + (size_t)g1 * HH + kt * 32 + kb * 8;
            short8 a, b;
            #pragma unroll
            for (int j = 0; j < 8; j++) { a[j] = (short)f2bf(s0[j]); b[j] = (short)f2bf(s1[j]); }
            bf0[kt] = a; bf1[kt] = b;
        }
    }

    for (int i = tid; i < 16 * HBP; i += 1024) hb[i] = 0;
    float c0 = 0.f, c1 = 0.f, h0 = 0.f, h1 = 0.f;
    __syncthreads();

    const size_t XPBUF = (size_t)32 * Tc * 16 * G4;
    const size_t O1BUF = (size_t)32 * Tc * 16 * HH;

    for (int c = 0; c < NC; c++) {
        wait_flag(&f_in[c]);
        if (IS_L1 && c >= 2) wait_flag(&f_guard[c - 2]);

        const float* xpc = xp + (size_t)(c & 1) * XPBUF + (size_t)bg * Tc * 16 * G4;
        float pre[8];
        #pragma unroll
        for (int nt = 0; nt < 2; nt++)
            #pragma unroll
            for (int r = 0; r < 4; r++)
                pre[nt * 4 + r] = xpc[(kb * 4 + r) * G4 + gbase + nt * 16 + lm];

        for (int tl = 0; tl < Tc; tl++) {
            f32x4 acc0 = {pre[0], pre[1], pre[2], pre[3]};
            f32x4 acc1 = {pre[4], pre[5], pre[6], pre[7]};
            if (tl + 1 < Tc) {
                const float* xn = xpc + (size_t)(tl + 1) * 16 * G4;
                #pragma unroll
                for (int nt = 0; nt < 2; nt++)
                    #pragma unroll
                    for (int r = 0; r < 4; r++)
                        pre[nt * 4 + r] = xn[(kb * 4 + r) * G4 + gbase + nt * 16 + lm];
            }
            #pragma unroll
            for (int kt = 0; kt < 4; kt++) {
                const short8 a = *(const short8*)&hb[lm * HBP + kt * 32 + kb * 8];
                acc0 = __builtin_amdgcn_mfma_f32_16x16x32_bf16(a, bf0[kt], acc0, 0, 0, 0);
                acc1 = __builtin_amdgcn_mfma_f32_16x16x32_bf16(a, bf1[kt], acc1, 0, 0, 0);
            }
            float av0[4], av1[4];
            if (type == 2) {
                #pragma unroll
                for (int r = 0; r < 4; r++) { av0[r] = tanhfast(acc0[r]); av1[r] = tanhfast(acc1[r]); }
            } else {
                #pragma unroll
                for (int r = 0; r < 4; r++) { av0[r] = sigf(acc0[r]); av1[r] = sigf(acc1[r]); }
            }
            #pragma unroll
            for (int r = 0; r < 4; r++) {
                abuf[(kb * 4 + r) * ABP + gbase + lm]      = av0[r];
                abuf[(kb * 4 + r) * ABP + gbase + 16 + lm] = av1[r];
            }
            __syncthreads();

            {
                const float* ab = &abuf[w * ABP];
                const float i0 = ab[l],      f0 = ab[HH + l];
                const float g0 = ab[2*HH+l], o0 = ab[3*HH + l];
                c0 = f0 * c0 + i0 * g0;
                h0 = o0 * tanhfast(c0);
                const float i1 = ab[64 + l],      f1 = ab[HH + 64 + l];
                const float g1 = ab[2*HH+64 + l], o1 = ab[3*HH + 64 + l];
                c1 = f1 * c1 + i1 * g1;
                h1 = o1 * tanhfast(c1);
                const unsigned short hb0 = f2bf(h0), hb1 = f2bf(h1);
                hb[w * HBP + l]      = hb0;
                hb[w * HBP + 64 + l] = hb1;
                if (IS_L1) {
                    unsigned short* op = out1 + (size_t)(c & 1) * O1BUF
                                       + ((size_t)(bg * Tc + tl) * 16 + w) * HH;
                    op[l] = hb0; op[64 + l] = hb1;
                }
            }
            __syncthreads();
        }
        set_flag(&f_done[c]);
    }

    if (!IS_L1) {
        h2s[(size_t)(bg * 16 + w) * HH + l]      = h0;
        h2s[(size_t)(bg * 16 + w) * HH + 64 + l] = h1;
    }
}

// ---------------------------------------------------------------------------
// xp1 worker: xp1[c] = x_chunk @ W1_ih^T + bias. A-frags loaded directly from
// global per lane (16-row t-slab is L1-cache hot across the 16 waves).
// ---------------------------------------------------------------------------
__device__ void xp1_worker(
    const float* __restrict__ x, const float* __restrict__ w_ih,
    const float* __restrict__ b_ih, const float* __restrict__ b_hh,
    float* __restrict__ xp1, int* __restrict__ f_xp1, int* __restrict__ f_l1d,
    int bg, int Tc, int NC)
{
    const int tid = threadIdx.x;
    const int w = tid >> 6, l = tid & 63, lm = l & 15, kb = l >> 4;
    const int gbase = w * 32, r0 = bg * 16;

    short8 bf0[2], bf1[2];
    float bv0, bv1;
    {
        const int g0 = gbase + lm, g1 = gbase + 16 + lm;
        bv0 = b_ih[g0] + b_hh[g0];
        bv1 = b_ih[g1] + b_hh[g1];
        #pragma unroll
        for (int kt = 0; kt < 2; kt++) {
            const float* s0 = w_ih + (size_t)g0 * FF + kt * 32 + kb * 8;
            const float* s1 = w_ih + (size_t)g1 * FF + kt * 32 + kb * 8;
            short8 a, b;
            #pragma unroll
            for (int j = 0; j < 8; j++) { a[j] = (short)f2bf(s0[j]); b[j] = (short)f2bf(s1[j]); }
            bf0[kt] = a; bf1[kt] = b;
        }
    }
    const size_t XPBUF = (size_t)32 * Tc * 16 * G4;

    for (int c = 0; c < NC; c++) {
        if (c >= 2) wait_flag(&f_l1d[c - 2]);
        for (int tl = 0; tl < Tc; tl++) {
            const int t = c * Tc + tl;
            short8 af[2];
            #pragma unroll
            for (int kt = 0; kt < 2; kt++) {
                const float* src = x + ((size_t)(r0 + lm) * TT + t) * FF + kt * 32 + kb * 8;
                short8 a;
                #pragma unroll
                for (int j = 0; j < 8; j++) a[j] = (short)f2bf(src[j]);
                af[kt] = a;
            }
            f32x4 acc0 = {bv0, bv0, bv0, bv0};
            f32x4 acc1 = {bv1, bv1, bv1, bv1};
            #pragma unroll
            for (int kt = 0; kt < 2; kt++) {
                acc0 = __builtin_amdgcn_mfma_f32_16x16x32_bf16(af[kt], bf0[kt], acc0, 0, 0, 0);
                acc1 = __builtin_amdgcn_mfma_f32_16x16x32_bf16(af[kt], bf1[kt], acc1, 0, 0, 0);
            }
            float* dst = xp1 + (size_t)(c & 1) * XPBUF + ((size_t)(bg * Tc + tl) * 16) * G4;
            #pragma unroll
            for (int r = 0; r < 4; r++) {
                dst[(kb * 4 + r) * G4 + gbase + lm]      = acc0[r];
                dst[(kb * 4 + r) * G4 + gbase + 16 + lm] = acc1[r];
            }
        }
        set_flag(&f_xp1[c]);
    }
}

// ---------------------------------------------------------------------------
// xp2 worker: xp2[c] = out1[c] @ W2_ih^T + bias. out1 already bf16.
// ---------------------------------------------------------------------------
__device__ void xp2_worker(
    const unsigned short* __restrict__ out1, const float* __restrict__ w_ih,
    const float* __restrict__ b_ih, const float* __restrict__ b_hh,
    float* __restrict__ xp2, int* __restrict__ f_l1d, int* __restrict__ f_l2d,
    int* __restrict__ f_xp2, int bg, int Tc, int NC)
{
    const int tid = threadIdx.x;
    const int w = tid >> 6, l = tid & 63, lm = l & 15, kb = l >> 4;
    const int gbase = w * 32;

    short8 bf0[4], bf1[4];
    float bv0, bv1;
    {
        const int g0 = gbase + lm, g1 = gbase + 16 + lm;
        bv0 = b_ih[g0] + b_hh[g0];
        bv1 = b_ih[g1] + b_hh[g1];
        #pragma unroll
        for (int kt = 0; kt < 4; kt++) {
            const float* s0 = w_ih + (size_t)g0 * HH + kt * 32 + kb * 8;
            const float* s1 = w_ih + (size_t)g1 * HH + kt * 32 + kb * 8;
            short8 a, b;
            #pragma unroll
            for (int j = 0; j < 8; j++) { a[j] = (short)f2bf(s0[j]); b[j] = (short)f2bf(s1[j]); }
            bf0[kt] = a; bf1[kt] = b;
        }
    }
    const size_t XPBUF = (size_t)32 * Tc * 16 * G4;
    const size_t O1BUF = (size_t)32 * Tc * 16 * HH;

    for (int c = 0; c < NC; c++) {
        wait_flag(&f_l1d[c]);
        if (c >= 2) wait_flag(&f_l2d[c - 2]);
        const unsigned short* src = out1 + (size_t)(c & 1) * O1BUF
                                  + (size_t)(bg * Tc) * 16 * HH;
        for (int tl = 0; tl < Tc; tl++) {
            const unsigned short* srow = src + (size_t)tl * 16 * HH + lm * HH + kb * 8;
            f32x4 acc0 = {bv0, bv0, bv0, bv0};
            f32x4 acc1 = {bv1, bv1, bv1, bv1};
            #pragma unroll
            for (int kt = 0; kt < 4; kt++) {
                const short8 a = *(const short8*)(srow + kt * 32);
                acc0 = __builtin_amdgcn_mfma_f32_16x16x32_bf16(a, bf0[kt], acc0, 0, 0, 0);
                acc1 = __builtin_amdgcn_mfma_f32_16x16x32_bf16(a, bf1[kt], acc1, 0, 0, 0);
            }
            float* dst = xp2 + (size_t)(c & 1) * XPBUF + ((size_t)(bg * Tc + tl) * 16) * G4;
            #pragma unroll
            for (int r = 0; r < 4; r++) {
                dst[(kb * 4 + r) * G4 + gbase + lm]      = acc0[r];
                dst[(kb * 4 + r) * G4 + gbase + 16 + lm] = acc1[r];
            }
        }
        set_flag(&f_xp2[c]);
    }
}

// ---------------------------------------------------------------------------
// 4-stage pipeline: bid 0-31 L1 scan | 32-63 L2 scan | 64-95 xp1 | 96-127 xp2.
// All stages for batch-group bg share bid%8 -> same XCD (L2 locality).
// ---------------------------------------------------------------------------
__global__ __launch_bounds__(1024, 1) void lstm_pipe(
    const float* __restrict__ x,
    const float* __restrict__ w1_ih, const float* __restrict__ w1_hh,
    const float* __restrict__ b1_ih, const float* __restrict__ b1_hh,
    const float* __restrict__ w2_ih, const float* __restrict__ w2_hh,
    const float* __restrict__ b2_ih, const float* __restrict__ b2_hh,
    float* __restrict__ xp1, float* __restrict__ xp2,
    unsigned short* __restrict__ out1, float* __restrict__ h2s,
    int* __restrict__ flags, int Tc, int NC)
{
    __shared__ __align__(16) unsigned short hb[16 * HBP];
    __shared__ __align__(16) float abuf[16 * ABP];

    int* f_xp1 = flags;                 // [32][NCMAX]
    int* f_l1d = flags + 32 * NCMAX;
    int* f_xp2 = flags + 64 * NCMAX;
    int* f_l2d = flags + 96 * NCMAX;

    const int bid = blockIdx.x;
    const int bg = bid & 31;
    if (bid < 32) {
        scan_layer<true >(xp1, w1_hh, out1, nullptr,
                          &f_xp1[bg * NCMAX], &f_l1d[bg * NCMAX], &f_xp2[bg * NCMAX],
                          bg, Tc, NC, hb, abuf);
    } else if (bid < 64) {
        scan_layer<false>(xp2, w2_hh, nullptr, h2s,
                          &f_xp2[bg * NCMAX], &f_l2d[bg * NCMAX], nullptr,
                          bg, Tc, NC, hb, abuf);
    } else if (bid < 96) {
        xp1_worker(x, w1_ih, b1_ih, b1_hh, xp1,
                   &f_xp1[bg * NCMAX], &f_l1d[bg * NCMAX], bg, Tc, NC);
    } else {
        xp2_worker(out1, w2_ih, b2_ih, b2_hh, xp2,
                   &f_l1d[bg * NCMAX], &f_l2d[bg * NCMAX], &f_xp2[bg * NCMAX],
                   bg, Tc, NC);
    }
}

__global__ void final_kernel(const float* __restrict__ h2s,
                             const float* __restrict__ w_fc,
                             const float* __restrict__ b_fc,
                             float* __restrict__ out)
{
    const int idx = blockIdx.x * blockDim.x + threadIdx.x;
    if (idx >= BB * NCLS) return;
    const int b = idx / NCLS, cls = idx % NCLS;
    const float* hp = h2s + (size_t)b * HH;
    const float* wp = w_fc + (size_t)cls * HH;
    float acc = b_fc[cls];
    #pragma unroll 8
    for (int k = 0; k < HH; k++) acc += hp[k] * wp[k];
    out[idx] = sigf(acc);
}

extern "C" void kernel_launch(void* const* d_in, const int* in_sizes, int n_in,
                              void* d_out, int out_size, void* d_ws, size_t ws_size,
                              hipStream_t stream)
{
    const float* x     = (const float*)d_in[0];
    const float* w1_ih = (const float*)d_in[1];
    const float* w1_hh = (const float*)d_in[2];
    const float* b1_ih = (const float*)d_in[3];
    const float* b1_hh = (const float*)d_in[4];
    const float* w2_ih = (const float*)d_in[5];
    const float* w2_hh = (const float*)d_in[6];
    const float* b2_ih = (const float*)d_in[7];
    const float* b2_hh = (const float*)d_in[8];
    const float* w_fc  = (const float*)d_in[9];
    const float* b_fc  = (const float*)d_in[10];
    float* out = (float*)d_out;

    // pick Tc (chunk steps): footprint = h2s + flags + 2x xp1 + 2x xp2 + 2x out1
    int Tc = 16;
    auto need = [](int tc) {
        return (size_t)BB * HH * 4 + 128 * NCMAX * 4
             + 2 * (2 * (size_t)BB * tc * G4 * 4)      // xp1 + xp2, dbuf, fp32
             + 2 * (size_t)BB * tc * HH * 2;           // out1, dbuf, bf16
    };
    while (Tc > 8 && need(Tc) > ws_size) Tc >>= 1;
    const int NC = TT / Tc;

    char* ws = (char*)d_ws;
    float* h2s = (float*)ws;                  ws += (size_t)BB * HH * 4;
    int* flags = (int*)ws;                    ws += 128 * NCMAX * 4;
    float* xp1 = (float*)ws;                  ws += 2 * (size_t)BB * Tc * G4 * 4;
    float* xp2 = (float*)ws;                  ws += 2 * (size_t)BB * Tc * G4 * 4;
    unsigned short* out1 = (unsigned short*)ws;

    hipMemsetAsync(flags, 0, 128 * NCMAX * 4, stream);
    lstm_pipe<<<128, 1024, 0, stream>>>(x, w1_ih, w1_hh, b1_ih, b1_hh,
                                        w2_ih, w2_hh, b2_ih, b2_hh,
                                        xp1, xp2, out1, h2s, flags, Tc, NC);
    final_kernel<<<(BB * NCLS + 255) / 256, 256, 0, stream>>>(h2s, w_fc, b_fc, out);
}

// Round 6
// 1253.695 us; speedup vs baseline: 3.0823x; 3.0823x over previous
//
#include <hip/hip_runtime.h>

#define BB 512
#define TT 512
#define FF 64
#define HH 128
#define G4 512
#define NCLS 10
#define WT 4            // LDS staging window (steps)
#define CH 16           // producer->consumer chunk (steps)
#define HBP 136         // padded h row (shorts): 272 B, 16B-divisible

typedef __attribute__((ext_vector_type(8))) short short8;
typedef __attribute__((ext_vector_type(4))) float f32x4;

__device__ __forceinline__ float sigf(float x) { return 1.0f / (1.0f + __expf(-x)); }
__device__ __forceinline__ float tanhfast(float x) { return 2.0f / (1.0f + __expf(-2.0f * x)) - 1.0f; }
__device__ __forceinline__ unsigned short f2bf(float f) {
    union { float f; unsigned u; } v; v.f = f;
    unsigned r = v.u + 0x7FFFu + ((v.u >> 16) & 1u);   // RNE
    return (unsigned short)(r >> 16);
}

// ---- flag protocol (round-4 proven) ---------------------------------------
__device__ __forceinline__ void wait_flag(int* f) {
    if (threadIdx.x == 0) {
        while (__hip_atomic_load(f, __ATOMIC_ACQUIRE, __HIP_MEMORY_SCOPE_AGENT) == 0)
            __builtin_amdgcn_s_sleep(2);
    }
    __syncthreads();
    (void)__hip_atomic_load(f, __ATOMIC_ACQUIRE, __HIP_MEMORY_SCOPE_AGENT);
}
__device__ __forceinline__ void set_flag(int* f) {
    __threadfence();
    __syncthreads();   // doubles as the per-step barrier on chunk-end steps
    if (threadIdx.x == 0)
        __hip_atomic_fetch_add(f, 1, __ATOMIC_RELEASE, __HIP_MEMORY_SCOPE_AGENT);
}

// ---------------------------------------------------------------------------
// Fused LSTM layer scan. One block = 16 batch rows, 512 threads = 8 waves.
// Wave w owns N-tiles {w, w+8, w+16, w+24} -> gates j*128 + 16w + lm for
// j=i,f,g,o. Hence lane (w,kb,lm) holds all 4 gate types for unit u=16w+lm,
// rows kb*4+r  -> state update fully in-lane, no LDS gate round-trip,
// ONE barrier per step. A = [x_t | h] bf16 from LDS; each A-frag read feeds
// 4 MFMAs. Weights bf16 stationary in VGPRs (KT*4 short8). x/out1 staged in
// double-buffered LDS windows of WT steps with register prefetch.
// ---------------------------------------------------------------------------
template<int XW, bool IS_L1>
__device__ void layer_scan(
    const void* __restrict__ xin_,
    const float* __restrict__ w_ih, const float* __restrict__ w_hh,
    const float* __restrict__ b_ih, const float* __restrict__ b_hh,
    unsigned short* __restrict__ out1,   // L1: h stream out (bf16)
    float* __restrict__ h2s,             // L2: final h out (fp32)
    int* __restrict__ f_in,              // L2: per-chunk input flags
    int* __restrict__ f_out,             // L1: per-chunk done flags
    int bg, unsigned short* xw, unsigned short* hb)
{
    const int tid = threadIdx.x;
    const int w = tid >> 6, l = tid & 63, lm = l & 15, kb = l >> 4;
    const int u = w * 16 + lm;           // owned hidden unit
    constexpr int KT  = (XW + HH) / 32;  // 6 (L1) / 8 (L2)
    constexpr int XKT = XW / 32;         // 2 / 4
    constexpr int XWP = XW + 8;          // padded LDS row (shorts)
    constexpr int XBUF = WT * 16 * XWP;  // one window buffer (shorts)

    // --- stationary B fragments + bias: gate g = j*128 + 16w + lm ---
    short8 bf[4][KT];
    float bv[4];
    #pragma unroll
    for (int j = 0; j < 4; j++) {
        const int g = j * 128 + w * 16 + lm;
        bv[j] = b_ih[g] + b_hh[g];
        #pragma unroll
        for (int kt = 0; kt < KT; kt++) {
            const int k0 = kt * 32 + kb * 8;
            const float* s = (k0 < XW) ? (w_ih + (size_t)g * XW + k0)
                                       : (w_hh + (size_t)g * HH + (k0 - XW));
            short8 t;
            #pragma unroll
            for (int q = 0; q < 8; q++) t[q] = (short)f2bf(s[q]);
            bf[j][kt] = t;
        }
    }

    for (int i = tid; i < 16 * HBP; i += 512) hb[i] = 0;

    float c[4] = {0.f, 0.f, 0.f, 0.f}, hlast[4] = {0.f, 0.f, 0.f, 0.f};

    // --- prefetch window 0 into registers ---
    float4 pfa, pfb;     // L1: 8 fp32
    uint4  pf0, pf1;     // L2: 16 bf16
    if (IS_L1) {
        const float* x = (const float*)xin_;
        const int flat = tid * 8;
        const int tt = flat >> 10, row = (flat >> 6) & 15, k = flat & 63;
        const float* s = x + (((size_t)(bg * 16 + row)) * TT + tt) * FF + k;
        pfa = *(const float4*)s; pfb = *(const float4*)(s + 4);
    } else {
        wait_flag(&f_in[0]);
        const unsigned short* o1 = (const unsigned short*)xin_;
        const int flat = tid * 16;
        const int tt = flat >> 11, row = (flat >> 7) & 15, k = flat & 127;
        const unsigned short* s = o1 + (((size_t)(bg * 16 + row)) * TT + tt) * HH + k;
        pf0 = *(const uint4*)s; pf1 = *(const uint4*)(s + 8);
    }

    for (int tl = 0; tl < TT; tl++) {
        if ((tl & (WT - 1)) == 0) {
            // commit prefetched window to LDS (dbuf: readers of this buf were
            // window-2, long done; the per-step barrier below publishes it)
            unsigned short* buf = xw + ((tl >> 2) & 1) * XBUF;
            if (IS_L1) {
                const int flat = tid * 8;
                const int tt = flat >> 10, row = (flat >> 6) & 15, k = flat & 63;
                uint4 pv;
                pv.x = (unsigned)f2bf(pfa.x) | ((unsigned)f2bf(pfa.y) << 16);
                pv.y = (unsigned)f2bf(pfa.z) | ((unsigned)f2bf(pfa.w) << 16);
                pv.z = (unsigned)f2bf(pfb.x) | ((unsigned)f2bf(pfb.y) << 16);
                pv.w = (unsigned)f2bf(pfb.z) | ((unsigned)f2bf(pfb.w) << 16);
                *(uint4*)&buf[(tt * 16 + row) * XWP + k] = pv;
            } else {
                const int flat = tid * 16;
                const int tt = flat >> 11, row = (flat >> 7) & 15, k = flat & 127;
                *(uint4*)&buf[(tt * 16 + row) * XWP + k]     = pf0;
                *(uint4*)&buf[(tt * 16 + row) * XWP + k + 8] = pf1;
            }
            __syncthreads();
            // issue prefetch for next window
            const int ws = tl + WT;
            if (ws < TT) {
                if (!IS_L1 && (ws & (CH - 1)) == 0) wait_flag(&f_in[ws >> 4]);
                if (IS_L1) {
                    const float* x = (const float*)xin_;
                    const int flat = tid * 8;
                    const int tt = flat >> 10, row = (flat >> 6) & 15, k = flat & 63;
                    const float* s = x + (((size_t)(bg * 16 + row)) * TT + ws + tt) * FF + k;
                    pfa = *(const float4*)s; pfb = *(const float4*)(s + 4);
                } else {
                    const unsigned short* o1 = (const unsigned short*)xin_;
                    const int flat = tid * 16;
                    const int tt = flat >> 11, row = (flat >> 7) & 15, k = flat & 127;
                    const unsigned short* s = o1 + (((size_t)(bg * 16 + row)) * TT + ws + tt) * HH + k;
                    pf0 = *(const uint4*)s; pf1 = *(const uint4*)(s + 8);
                }
            }
        }
        const int tloc = tl & (WT - 1);
        const unsigned short* abase = xw + ((tl >> 2) & 1) * XBUF
                                    + (tloc * 16 + lm) * XWP + kb * 8;
        const unsigned short* hbase = hb + lm * HBP + kb * 8;

        f32x4 a0 = {bv[0], bv[0], bv[0], bv[0]};
        f32x4 a1 = {bv[1], bv[1], bv[1], bv[1]};
        f32x4 a2 = {bv[2], bv[2], bv[2], bv[2]};
        f32x4 a3 = {bv[3], bv[3], bv[3], bv[3]};
        #pragma unroll
        for (int kt = 0; kt < KT; kt++) {
            const unsigned short* ap = (kt < XKT) ? (abase + kt * 32)
                                                  : (hbase + (kt - XKT) * 32);
            const short8 a = *(const short8*)ap;
            a0 = __builtin_amdgcn_mfma_f32_16x16x32_bf16(a, bf[0][kt], a0, 0, 0, 0);
            a1 = __builtin_amdgcn_mfma_f32_16x16x32_bf16(a, bf[1][kt], a1, 0, 0, 0);
            a2 = __builtin_amdgcn_mfma_f32_16x16x32_bf16(a, bf[2][kt], a2, 0, 0, 0);
            a3 = __builtin_amdgcn_mfma_f32_16x16x32_bf16(a, bf[3][kt], a3, 0, 0, 0);
        }

        // ---- in-lane epilogue: unit u, rows kb*4+r ----
        #pragma unroll
        for (int r = 0; r < 4; r++) {
            const float iv = sigf(a0[r]);
            const float fv = sigf(a1[r]);
            const float gv = tanhfast(a2[r]);
            const float ov = sigf(a3[r]);
            c[r] = fv * c[r] + iv * gv;
            const float h = ov * tanhfast(c[r]);
            hlast[r] = h;
            const unsigned short h16 = f2bf(h);
            hb[(kb * 4 + r) * HBP + u] = h16;
            if (IS_L1)
                out1[(((size_t)(bg * 16 + kb * 4 + r)) * TT + tl) * HH + u] = h16;
        }

        if (IS_L1 && (tl & (CH - 1)) == (CH - 1)) {
            set_flag(&f_out[tl >> 4]);   // fence + barrier + flag
        } else {
            __syncthreads();             // publish h for next step
        }
    }

    if (!IS_L1) {
        #pragma unroll
        for (int r = 0; r < 4; r++)
            h2s[((size_t)(bg * 16 + kb * 4 + r)) * HH + u] = hlast[r];
    }
}

// bid 0-31: layer-1 scan (producer). bid 32-63: layer-2 scan (consumer).
// bid and bid+32 share bid%8 -> same XCD for out1 L2-cache locality.
__global__ __launch_bounds__(512, 1) void lstm_pipe(
    const float* __restrict__ x,
    const float* __restrict__ w1_ih, const float* __restrict__ w1_hh,
    const float* __restrict__ b1_ih, const float* __restrict__ b1_hh,
    const float* __restrict__ w2_ih, const float* __restrict__ w2_hh,
    const float* __restrict__ b2_ih, const float* __restrict__ b2_hh,
    unsigned short* __restrict__ out1, float* __restrict__ h2s,
    int* __restrict__ flags)
{
    __shared__ __align__(16) unsigned short xw[2 * WT * 16 * (HH + 8)]; // 34816 B (L2 max)
    __shared__ __align__(16) unsigned short hb[16 * HBP];               //  4352 B
    const int bid = blockIdx.x;
    if (bid < 32)
        layer_scan<FF, true >(x, w1_ih, w1_hh, b1_ih, b1_hh, out1, nullptr,
                              nullptr, &flags[bid * 32], bid, xw, hb);
    else
        layer_scan<HH, false>(out1, w2_ih, w2_hh, b2_ih, b2_hh, nullptr, h2s,
                              &flags[(bid - 32) * 32], nullptr, bid - 32, xw, hb);
}

__global__ void final_kernel(const float* __restrict__ h2s,
                             const float* __restrict__ w_fc,
                             const float* __restrict__ b_fc,
                             float* __restrict__ out)
{
    const int idx = blockIdx.x * blockDim.x + threadIdx.x;
    if (idx >= BB * NCLS) return;
    const int b = idx / NCLS, cls = idx % NCLS;
    const float* hp = h2s + (size_t)b * HH;
    const float* wp = w_fc + (size_t)cls * HH;
    float acc = b_fc[cls];
    #pragma unroll 8
    for (int k = 0; k < HH; k++) acc += hp[k] * wp[k];
    out[idx] = sigf(acc);
}

extern "C" void kernel_launch(void* const* d_in, const int* in_sizes, int n_in,
                              void* d_out, int out_size, void* d_ws, size_t ws_size,
                              hipStream_t stream)
{
    const float* x     = (const float*)d_in[0];
    const float* w1_ih = (const float*)d_in[1];
    const float* w1_hh = (const float*)d_in[2];
    const float* b1_ih = (const float*)d_in[3];
    const float* b1_hh = (const float*)d_in[4];
    const float* w2_ih = (const float*)d_in[5];
    const float* w2_hh = (const float*)d_in[6];
    const float* b2_ih = (const float*)d_in[7];
    const float* b2_hh = (const float*)d_in[8];
    const float* w_fc  = (const float*)d_in[9];
    const float* b_fc  = (const float*)d_in[10];
    float* out = (float*)d_out;

    // workspace: [h2s fp32 256KB | flags 4KB | out1 bf16 67MB]
    char* ws = (char*)d_ws;
    float* h2s = (float*)ws;                 ws += (size_t)BB * HH * sizeof(float);
    int* flags = (int*)ws;                   ws += 32 * 32 * sizeof(int);
    unsigned short* out1 = (unsigned short*)ws;

    hipMemsetAsync(flags, 0, 32 * 32 * sizeof(int), stream);
    lstm_pipe<<<64, 512, 0, stream>>>(x, w1_ih, w1_hh, b1_ih, b1_hh,
                                      w2_ih, w2_hh, b2_ih, b2_hh,
                                      out1, h2s, flags);
    final_kernel<<<(BB * NCLS + 255) / 256, 256, 0, stream>>>(h2s, w_fc, b_fc, out);
}